// Round 1
// baseline (28.021 us; speedup 1.0000x reference)
//
#include <hip/hip_runtime.h>
#include <hip/hip_bf16.h>

// Problem constants (match reference)
#define KCLS 8192
#define DFEAT 64
#define BATCH_N 16384
#define LAMB 0.01
#define LAMB1 10.0

constexpr int NBLK_C = 32;  // blocks working on centers -> S partials
constexpr int NBLK_B = 64;  // blocks working on center-loss

// ws layout (floats): [0 .. NBLK_C*64)       : S partials, one 64-vector per center-block
//                     [NBLK_C*64 .. +NBLK_B) : center-loss partials, one per batch-block
__global__ __launch_bounds__(256) void illoss_fused(const int* __restrict__ y,
                                                    const float* __restrict__ feat,
                                                    const float* __restrict__ centers,
                                                    float* __restrict__ ws) {
    const int tid  = threadIdx.x;
    const int lane = tid & 63;
    const int wave = tid >> 6;           // 0..3
    const int blk  = blockIdx.x;

    if (blk < NBLK_C) {
        // ---- S = sum_k centers[k]/||centers[k]||, per-lane component `lane` ----
        const int wid    = blk * 4 + wave;        // global wave id 0..127
        const int nwaves = NBLK_C * 4;            // 128
        float acc = 0.0f;
        for (int k = wid; k < KCLS; k += nwaves) {
            float v  = centers[k * DFEAT + lane];
            float ss = v * v;
            #pragma unroll
            for (int off = 32; off > 0; off >>= 1) ss += __shfl_xor(ss, off, 64);
            acc += v * __frsqrt_rn(ss);           // v / ||c_k||
        }
        __shared__ float sacc[256];
        sacc[tid] = acc;
        __syncthreads();
        if (wave == 0) {
            float s = sacc[lane] + sacc[64 + lane] + sacc[128 + lane] + sacc[192 + lane];
            ws[blk * 64 + lane] = s;
        }
    } else {
        // ---- loss_cen partial: sum_i ||feat[i] - centers[y[i]]||^2 ----
        const int bblk   = blk - NBLK_C;
        const int wid    = bblk * 4 + wave;       // 0..255
        const int nwaves = NBLK_B * 4;            // 256
        float acc = 0.0f;
        for (int i = wid; i < BATCH_N; i += nwaves) {
            int cls = y[i];
            float d = feat[i * DFEAT + lane] - centers[cls * DFEAT + lane];
            acc += d * d;
        }
        #pragma unroll
        for (int off = 32; off > 0; off >>= 1) acc += __shfl_xor(acc, off, 64);
        __shared__ float wacc[4];
        if (lane == 0) wacc[wave] = acc;
        __syncthreads();
        if (tid == 0) ws[NBLK_C * 64 + bblk] = wacc[0] + wacc[1] + wacc[2] + wacc[3];
    }
}

__global__ __launch_bounds__(64) void illoss_final(const float* __restrict__ ws,
                                                   float* __restrict__ out) {
    const int lane = threadIdx.x;
    // reduce S partials: S[lane]
    float S = 0.0f;
    #pragma unroll
    for (int b = 0; b < NBLK_C; ++b) S += ws[b * 64 + lane];
    float s2 = S * S;
    #pragma unroll
    for (int off = 32; off > 0; off >>= 1) s2 += __shfl_xor(s2, off, 64);
    if (lane == 0) {
        float cen = 0.0f;
        for (int i = 0; i < NBLK_B; ++i) cen += ws[NBLK_C * 64 + i];
        double loss_cen = 0.5 * (double)cen / (double)BATCH_N;
        // sum_offdiag cos = |S|^2 - K ; loss_ang = that + K*(K-1)
        double loss_ang = (double)s2 - (double)KCLS + (double)KCLS * (double)(KCLS - 1);
        out[0] = (float)(LAMB * (loss_cen + LAMB1 * loss_ang));
    }
}

extern "C" void kernel_launch(void* const* d_in, const int* in_sizes, int n_in,
                              void* d_out, int out_size, void* d_ws, size_t ws_size,
                              hipStream_t stream) {
    const int*   y       = (const int*)d_in[0];
    const float* feat    = (const float*)d_in[1];
    const float* centers = (const float*)d_in[2];
    float* out = (float*)d_out;
    float* ws  = (float*)d_ws;

    illoss_fused<<<NBLK_C + NBLK_B, 256, 0, stream>>>(y, feat, centers, ws);
    illoss_final<<<1, 64, 0, stream>>>(ws, out);
}

// Round 2
// 11.705 us; speedup vs baseline: 2.3940x; 2.3940x over previous
//
#include <hip/hip_runtime.h>
#include <hip/hip_bf16.h>

#define KCLS 8192
#define DFEAT 64
#define BATCH_N 16384
#define LAMB 0.01
#define LAMB1 10.0

constexpr int NBLK_C = 128;   // S-path blocks: 512 waves x 4 iters x 4 rows  = 8192 rows
constexpr int NBLK_B = 256;   // center-loss blocks: 1024 waves x 4 iters x 4 items = 16384 items

// ws layout (floats): [0 .. NBLK_C*64)            : per-block S partial 64-vectors
//                     [NBLK_C*64 .. +NBLK_B)      : per-block center-loss partial scalars
__global__ __launch_bounds__(256) void illoss_fused(const int* __restrict__ y,
                                                    const float* __restrict__ feat,
                                                    const float* __restrict__ centers,
                                                    float* __restrict__ ws) {
    const int tid  = threadIdx.x;
    const int lane = tid & 63;
    const int wave = tid >> 6;
    const int blk  = blockIdx.x;
    const float4* __restrict__ centers4 = (const float4*)centers;

    __shared__ float sacc[4][16][4];  // S path: per-wave partial vectors
    __shared__ float wacc[4];         // B path: per-wave partial scalars

    if (blk < NBLK_C) {
        // ---- S = sum_k centers[k]/||centers[k]|| ----
        // Wave loads 64 float4 = 1024B = 4 consecutive rows. Lane group g=lane>>4
        // holds row (base+g); lane l holds components 4*(l&15)..4*(l&15)+3.
        const int gwid = blk * 4 + wave;          // 0..511
        float ax = 0.f, ay = 0.f, az = 0.f, aw = 0.f;
        #pragma unroll
        for (int it = 0; it < 4; ++it) {
            const int row0 = gwid * 16 + it * 4;  // first of 4 rows this iter
            float4 v = centers4[row0 * 16 + lane];
            float ss = v.x * v.x + v.y * v.y + v.z * v.z + v.w * v.w;
            ss += __shfl_xor(ss, 1, 64);
            ss += __shfl_xor(ss, 2, 64);
            ss += __shfl_xor(ss, 4, 64);
            ss += __shfl_xor(ss, 8, 64);          // 16-lane group = one row's ||c||^2
            float inv = __frsqrt_rn(ss);
            ax += v.x * inv; ay += v.y * inv; az += v.z * inv; aw += v.w * inv;
        }
        // fold the 4 row-groups together (same component slots)
        ax += __shfl_xor(ax, 16, 64); ay += __shfl_xor(ay, 16, 64);
        az += __shfl_xor(az, 16, 64); aw += __shfl_xor(aw, 16, 64);
        ax += __shfl_xor(ax, 32, 64); ay += __shfl_xor(ay, 32, 64);
        az += __shfl_xor(az, 32, 64); aw += __shfl_xor(aw, 32, 64);
        if (lane < 16) {
            sacc[wave][lane][0] = ax; sacc[wave][lane][1] = ay;
            sacc[wave][lane][2] = az; sacc[wave][lane][3] = aw;
        }
        __syncthreads();
        if (tid < 64) {
            const int c = tid;  // component
            float s = sacc[0][c >> 2][c & 3] + sacc[1][c >> 2][c & 3]
                    + sacc[2][c >> 2][c & 3] + sacc[3][c >> 2][c & 3];
            ws[blk * 64 + c] = s;
        }
    } else {
        // ---- loss_cen partial: sum_i ||feat[i] - centers[y[i]]||^2 ----
        // Wave handles 16 items; 4 items per iteration via float4 loads.
        const int bblk = blk - NBLK_C;
        const int gwid = bblk * 4 + wave;         // 0..1023
        const int base = gwid * 16;
        const float4* __restrict__ feat4 = (const float4*)feat;
        int cls[4];
        #pragma unroll
        for (int it = 0; it < 4; ++it) cls[it] = y[base + it * 4 + (lane >> 4)];
        float acc = 0.f;
        #pragma unroll
        for (int it = 0; it < 4; ++it) {
            float4 f = feat4[(base + it * 4) * 16 + lane];
            float4 c = centers4[cls[it] * 16 + (lane & 15)];
            float dx = f.x - c.x, dy = f.y - c.y, dz = f.z - c.z, dw = f.w - c.w;
            acc += dx * dx + dy * dy + dz * dz + dw * dw;
        }
        acc += __shfl_xor(acc, 1, 64);
        acc += __shfl_xor(acc, 2, 64);
        acc += __shfl_xor(acc, 4, 64);
        acc += __shfl_xor(acc, 8, 64);
        acc += __shfl_xor(acc, 16, 64);
        acc += __shfl_xor(acc, 32, 64);
        if (lane == 0) wacc[wave] = acc;
        __syncthreads();
        if (tid == 0) ws[NBLK_C * 64 + bblk] = wacc[0] + wacc[1] + wacc[2] + wacc[3];
    }
}

__global__ __launch_bounds__(64) void illoss_final(const float* __restrict__ ws,
                                                   float* __restrict__ out) {
    const int lane = threadIdx.x;
    // S[lane] over 128 block-partials, 4 independent accumulators for ILP
    float s0 = 0.f, s1 = 0.f, s2a = 0.f, s3 = 0.f;
    #pragma unroll
    for (int b = 0; b < NBLK_C; b += 4) {
        s0 += ws[(b + 0) * 64 + lane];
        s1 += ws[(b + 1) * 64 + lane];
        s2a += ws[(b + 2) * 64 + lane];
        s3 += ws[(b + 3) * 64 + lane];
    }
    float S = (s0 + s1) + (s2a + s3);
    float s2 = S * S;
    s2 += __shfl_xor(s2, 1, 64);
    s2 += __shfl_xor(s2, 2, 64);
    s2 += __shfl_xor(s2, 4, 64);
    s2 += __shfl_xor(s2, 8, 64);
    s2 += __shfl_xor(s2, 16, 64);
    s2 += __shfl_xor(s2, 32, 64);
    // center-loss partials: 256 scalars, 4 per lane
    const float* cw = ws + NBLK_C * 64;
    float cacc = cw[lane] + cw[lane + 64] + cw[lane + 128] + cw[lane + 192];
    cacc += __shfl_xor(cacc, 1, 64);
    cacc += __shfl_xor(cacc, 2, 64);
    cacc += __shfl_xor(cacc, 4, 64);
    cacc += __shfl_xor(cacc, 8, 64);
    cacc += __shfl_xor(cacc, 16, 64);
    cacc += __shfl_xor(cacc, 32, 64);
    if (lane == 0) {
        double loss_cen = 0.5 * (double)cacc / (double)BATCH_N;
        double loss_ang = (double)s2 - (double)KCLS + (double)KCLS * (double)(KCLS - 1);
        out[0] = (float)(LAMB * (loss_cen + LAMB1 * loss_ang));
    }
}

extern "C" void kernel_launch(void* const* d_in, const int* in_sizes, int n_in,
                              void* d_out, int out_size, void* d_ws, size_t ws_size,
                              hipStream_t stream) {
    const int*   y       = (const int*)d_in[0];
    const float* feat    = (const float*)d_in[1];
    const float* centers = (const float*)d_in[2];
    float* out = (float*)d_out;
    float* ws  = (float*)d_ws;

    illoss_fused<<<NBLK_C + NBLK_B, 256, 0, stream>>>(y, feat, centers, ws);
    illoss_final<<<1, 64, 0, stream>>>(ws, out);
}